// Round 6
// baseline (730.210 us; speedup 1.0000x reference)
//
#include <hip/hip_runtime.h>
#include <hip/hip_bf16.h>

// ContrastiveLoss: z (8192x1024 fp32) -> scalar
//   zn = z / max(||z||,eps); S = zn@zn^T; diag=MASK; /T; nll = -S[i,i^4096] + lse(S[i,:]); mean
// R6: MX-scaled fp8 GEMM (mfma_scale 16x16x128, unit scales == plain fp8 math,
// 2x rate, K=128/instr). 256x256 lower-tri tiles, BK=128 stages double-buffered
// in 128KB LDS, 128B rows + chunk^(row&7) swizzle; all fragment reads are b128
// (the R4-verified 0-conflict quarter-wave geometry). R4 epilogue (plain stores
// + device atomicAdd) and separate k_final restored.

#define N 8192
#define D 1024
#define INV_T 14.285714285714286f
#define NTILES 528
#define ACC_SCALE (INV_T / 1024.0f)  // undo fp8 x32 scaling on both operands

typedef float f32x4 __attribute__((ext_vector_type(4)));
typedef int i32x4 __attribute__((ext_vector_type(4)));
typedef int i32x8 __attribute__((ext_vector_type(8)));
#define UNIT_SCALES 0x7F7F7F7F  // E8M0 = 127 -> 2^0 in every byte

__device__ inline void gload16(const void* g, void* l) {
  __builtin_amdgcn_global_load_lds(
      (const __attribute__((address_space(1))) void*)g,
      (__attribute__((address_space(3))) void*)l, 16, 0, 0);
}

// Phase 1: row-normalize z, scale x32, cast fp8 e4m3 -> zn8; zero rowsum.
__global__ __launch_bounds__(256) void k_normalize(const float* __restrict__ z,
                                                   unsigned char* __restrict__ zn8,
                                                   float* __restrict__ rowsum) {
  const int row = blockIdx.x;
  const int t = threadIdx.x;
  if (row < 32) rowsum[row * 256 + t] = 0.0f;
  const float4 v = ((const float4*)(z + (size_t)row * D))[t];
  float ss = v.x * v.x + v.y * v.y + v.z * v.z + v.w * v.w;
#pragma unroll
  for (int off = 32; off > 0; off >>= 1) ss += __shfl_down(ss, off, 64);
  __shared__ float red[4];
  __shared__ float s_inv;
  if ((t & 63) == 0) red[t >> 6] = ss;
  __syncthreads();
  if (t == 0) {
    float tot = red[0] + red[1] + red[2] + red[3];
    s_inv = 1.0f / fmaxf(sqrtf(tot), 1e-8f);
  }
  __syncthreads();
  const float sc = s_inv * 32.0f;  // e4m3 normal range; undone by ACC_SCALE
  int p = __builtin_amdgcn_cvt_pk_fp8_f32(v.x * sc, v.y * sc, 0, false);
  p = __builtin_amdgcn_cvt_pk_fp8_f32(v.z * sc, v.w * sc, p, true);
  ((int*)(zn8 + (size_t)row * D))[t] = p;
}

// Phase 2: 256x256 lower-triangle tile per block, 512 threads (8 waves, 4x2).
// fp8 BK=128: per buffer A 32KB + B 32KB; double-buffered = 128KB dynamic LDS.
// Rows 128B (8 x 16B chunks), logical chunk c stored at phys c^(r&7). Fragment
// = 32B/lane, read as two b128 at logical chunks 2kg/2kg+1 (quarter-wave 2-way,
// measured 0 conflicts in R4). One 16x16x128 mfma_scale per frag pair.
__global__ __launch_bounds__(512, 2) void k_tile(const unsigned char* __restrict__ zn8,
                                                 float* __restrict__ rowsum,
                                                 float* __restrict__ pos) {
  extern __shared__ __align__(16) char smem[];  // 131072
  const int tid = threadIdx.x;
  const int w = tid >> 6, l = tid & 63;

  // decode blockIdx -> lower-triangle (tr, tc), tr >= tc, over 32x32 tile grid
  const int b = blockIdx.x;
  int tr = (int)((sqrtf(8.0f * (float)b + 1.0f) - 1.0f) * 0.5f);
  if (tr * (tr + 1) / 2 > b) --tr;
  if ((tr + 1) * (tr + 2) / 2 <= b) ++tr;
  const int tc = b - tr * (tr + 1) / 2;
  const bool diag = (tr == tc);

  const int wr = w >> 1, wc = w & 1;
  const int m = l & 15, kg = l >> 4;
  const int rowA0 = tr * 256, colB0 = tc * 256;

  f32x4 acc[4][8] = {};

  // staging: per matrix per stage 2048 slots x 16B (256 rows x 8 chunks).
  // phys slot s -> row s>>3; phys chunk s&7 holds logical chunk (s&7)^(row&7).
  int srow[4], scol[4];
#pragma unroll
  for (int j = 0; j < 4; ++j) {
    int s = j * 512 + tid;
    int r = s >> 3;
    srow[j] = r;
    scol[j] = (s & 7) ^ (r & 7);
  }

  // fragment read offsets within a 128B row: logical chunks 2kg, 2kg+1
  const int csw0 = ((2 * kg) ^ (m & 7)) * 16;
  const int csw1 = ((2 * kg + 1) ^ (m & 7)) * 16;

  // prologue: stage kt=0 into buffer 0
  {
    char* ab = smem;
    char* bb = smem + 32768;
#pragma unroll
    for (int j = 0; j < 4; ++j) {
      const int s = j * 512 + tid;
      gload16((const char*)zn8 + ((size_t)(rowA0 + srow[j]) * D + scol[j] * 16), ab + s * 16);
    }
    if (!diag) {
#pragma unroll
      for (int j = 0; j < 4; ++j) {
        const int s = j * 512 + tid;
        gload16((const char*)zn8 + ((size_t)(colB0 + srow[j]) * D + scol[j] * 16), bb + s * 16);
      }
    }
  }
  __syncthreads();

  for (int kt = 0; kt < 8; ++kt) {
    if (kt < 7) {  // async prefetch kt+1 into other buffer; overlaps MFMA below
      const size_t kb = (size_t)(kt + 1) * 128;
      char* ab = smem + ((kt + 1) & 1) * 65536;
#pragma unroll
      for (int j = 0; j < 4; ++j) {
        const int s = j * 512 + tid;
        gload16((const char*)zn8 + ((size_t)(rowA0 + srow[j]) * D + kb + scol[j] * 16), ab + s * 16);
      }
      if (!diag) {
        char* bb = ab + 32768;
#pragma unroll
        for (int j = 0; j < 4; ++j) {
          const int s = j * 512 + tid;
          gload16((const char*)zn8 + ((size_t)(colB0 + srow[j]) * D + kb + scol[j] * 16), bb + s * 16);
        }
      }
    }
    const char* ab = smem + (kt & 1) * 65536;
    const char* bb = diag ? ab : (ab + 32768);

    // hold all 4 A frags (32 VGPR); stream B frags
    i32x8 af[4];
#pragma unroll
    for (int mt = 0; mt < 4; ++mt) {
      const char* rp = ab + (wr * 64 + mt * 16 + m) * 128;
      af[mt] = __builtin_shufflevector(*(const i32x4*)(rp + csw0), *(const i32x4*)(rp + csw1),
                                       0, 1, 2, 3, 4, 5, 6, 7);
    }
#pragma unroll
    for (int nt = 0; nt < 8; ++nt) {
      const char* rp = bb + (wc * 128 + nt * 16 + m) * 128;
      const i32x8 bf = __builtin_shufflevector(*(const i32x4*)(rp + csw0), *(const i32x4*)(rp + csw1),
                                               0, 1, 2, 3, 4, 5, 6, 7);
#pragma unroll
      for (int mt = 0; mt < 4; ++mt)
        acc[mt][nt] = __builtin_amdgcn_mfma_scale_f32_16x16x128_f8f6f4(
            af[mt], bf, acc[mt][nt], 0, 0, 0, UNIT_SCALES, 0, UNIT_SCALES);
    }
    __syncthreads();  // drains prefetch (vmcnt) + guards buffer reuse
  }

  // Epilogue. C/D layout: col=l&15, row=(l>>4)*4+reg.
  const int quad = l >> 4;
  const int col = l & 15;
  float cs[8] = {0.f, 0.f, 0.f, 0.f, 0.f, 0.f, 0.f, 0.f};
#pragma unroll
  for (int mt = 0; mt < 4; ++mt) {
    float rs[4] = {0.f, 0.f, 0.f, 0.f};
#pragma unroll
    for (int nt = 0; nt < 8; ++nt) {
      const int gcol = colB0 + wc * 128 + nt * 16 + col;
#pragma unroll
      for (int r = 0; r < 4; ++r) {
        const int grow = rowA0 + wr * 64 + mt * 16 + quad * 4 + r;
        const float t = acc[mt][nt][r] * ACC_SCALE;
        if (gcol == (grow ^ (N / 2))) {  // pos pair; never in diag tiles
          pos[grow] = t;
          pos[gcol] = t;  // S symmetric
        }
        const float e = (gcol == grow) ? 0.0f : __expf(t - INV_T);
        rs[r] += e;
        cs[nt] += e;
      }
    }
#pragma unroll
    for (int off = 1; off < 16; off <<= 1) {
#pragma unroll
      for (int r = 0; r < 4; ++r) rs[r] += __shfl_xor(rs[r], off, 64);
    }
    if (col == 0) {
#pragma unroll
      for (int r = 0; r < 4; ++r)
        atomicAdd(&rowsum[rowA0 + wr * 64 + mt * 16 + quad * 4 + r], rs[r]);
    }
  }
  if (!diag) {  // col sums = row-sums for block tc rows (symmetry)
#pragma unroll
    for (int nt = 0; nt < 8; ++nt) {
      cs[nt] += __shfl_xor(cs[nt], 16, 64);
      cs[nt] += __shfl_xor(cs[nt], 32, 64);
    }
    if (l < 16) {
#pragma unroll
      for (int nt = 0; nt < 8; ++nt)
        atomicAdd(&rowsum[colB0 + wc * 128 + nt * 16 + l], cs[nt]);
    }
  }
}

// Phase 3: single block: out = mean(-pos + C + log(rowsum)).
__global__ __launch_bounds__(1024) void k_final(const float* __restrict__ rowsum,
                                                const float* __restrict__ pos,
                                                float* __restrict__ out) {
  const int t = threadIdx.x;
  float s = 0.f;
  for (int i = t; i < N; i += 1024) s += INV_T + __logf(rowsum[i]) - pos[i];
#pragma unroll
  for (int off = 32; off > 0; off >>= 1) s += __shfl_down(s, off, 64);
  __shared__ float red[16];
  if ((t & 63) == 0) red[t >> 6] = s;
  __syncthreads();
  if (t == 0) {
    float tot = 0.f;
#pragma unroll
    for (int j = 0; j < 16; ++j) tot += red[j];
    out[0] = tot * (1.0f / N);
  }
}

extern "C" void kernel_launch(void* const* d_in, const int* in_sizes, int n_in,
                              void* d_out, int out_size, void* d_ws, size_t ws_size,
                              hipStream_t stream) {
  const float* z = (const float*)d_in[0];
  float* out = (float*)d_out;
  char* ws = (char*)d_ws;
  unsigned char* zn8 = (unsigned char*)ws;                    // 8 MiB fp8
  float* rowsum = (float*)(ws + (size_t)N * D);               // 32 KiB
  float* pos = (float*)(ws + (size_t)N * D + (size_t)N * 4);  // 32 KiB

  static bool attr_set = false;
  if (!attr_set) {  // host-side attribute, idempotent, not a stream op
    hipFuncSetAttribute((const void*)k_tile,
                        hipFuncAttributeMaxDynamicSharedMemorySize, 131072);
    attr_set = true;
  }

  k_normalize<<<N, 256, 0, stream>>>(z, zn8, rowsum);
  k_tile<<<NTILES, 512, 131072, stream>>>(zn8, rowsum, pos);
  k_final<<<1, 1024, 0, stream>>>(rowsum, pos, out);
}

// Round 7
// 146.556 us; speedup vs baseline: 4.9825x; 4.9825x over previous
//
#include <hip/hip_runtime.h>
#include <hip/hip_bf16.h>

// ContrastiveLoss: z (8192x1024 fp32) -> scalar
//   zn = z / max(||z||,eps); S = zn@zn^T; diag=MASK; /T; nll = -S[i,i^4096] + lse(S[i,:]); mean
// R7: plain fp8 e4m3 16x16x32 MFMA (long operands — no wide-vector spills) with
// K-PERMUTED b128 fragment reads: each lane reads 2 b128 at logical chunks kg,
// kg+4 (32B = all 4 K-steps of a BK=128 stage); step s uses the s-th 8-byte
// half. Dot products are K-order-invariant and A/B use the same permutation.
// Geometry (128B rows, chunk^(row&7) swizzle, quarter-wave b128) is exactly
// R4's measured-0-conflict layout. 256x256 lower-tri tiles, double-buffered
// 128KB LDS, 8 stages. Fixed-shift logsumexp partials via atomicAdd.

#define N 8192
#define D 1024
#define INV_T 14.285714285714286f
#define NTILES 528
#define ACC_SCALE (INV_T / 1024.0f)  // undo fp8 x32 scaling on both operands

typedef float f32x4 __attribute__((ext_vector_type(4)));
typedef long lx2 __attribute__((ext_vector_type(2)));

__device__ inline void gload16(const void* g, void* l) {
  __builtin_amdgcn_global_load_lds(
      (const __attribute__((address_space(1))) void*)g,
      (__attribute__((address_space(3))) void*)l, 16, 0, 0);
}

// Phase 1: row-normalize z, scale x32, cast fp8 e4m3 -> zn8; zero rowsum.
__global__ __launch_bounds__(256) void k_normalize(const float* __restrict__ z,
                                                   unsigned char* __restrict__ zn8,
                                                   float* __restrict__ rowsum) {
  const int row = blockIdx.x;
  const int t = threadIdx.x;
  if (row < 32) rowsum[row * 256 + t] = 0.0f;
  const float4 v = ((const float4*)(z + (size_t)row * D))[t];
  float ss = v.x * v.x + v.y * v.y + v.z * v.z + v.w * v.w;
#pragma unroll
  for (int off = 32; off > 0; off >>= 1) ss += __shfl_down(ss, off, 64);
  __shared__ float red[4];
  __shared__ float s_inv;
  if ((t & 63) == 0) red[t >> 6] = ss;
  __syncthreads();
  if (t == 0) {
    float tot = red[0] + red[1] + red[2] + red[3];
    s_inv = 1.0f / fmaxf(sqrtf(tot), 1e-8f);
  }
  __syncthreads();
  const float sc = s_inv * 32.0f;  // e4m3 normal range; undone by ACC_SCALE
  int p = __builtin_amdgcn_cvt_pk_fp8_f32(v.x * sc, v.y * sc, 0, false);
  p = __builtin_amdgcn_cvt_pk_fp8_f32(v.z * sc, v.w * sc, p, true);
  ((int*)(zn8 + (size_t)row * D))[t] = p;
}

// Phase 2: 256x256 lower-triangle tile per block, 512 threads (8 waves, 4x2).
// fp8 BK=128: per buffer A 32KB + B 32KB; double-buffered = 128KB dynamic LDS.
__global__ __launch_bounds__(512, 2) void k_tile(const unsigned char* __restrict__ zn8,
                                                 float* __restrict__ rowsum,
                                                 float* __restrict__ pos) {
  extern __shared__ __align__(16) char smem[];  // 131072
  const int tid = threadIdx.x;
  const int w = tid >> 6, l = tid & 63;

  // decode blockIdx -> lower-triangle (tr, tc), tr >= tc, over 32x32 tile grid
  const int b = blockIdx.x;
  int tr = (int)((sqrtf(8.0f * (float)b + 1.0f) - 1.0f) * 0.5f);
  if (tr * (tr + 1) / 2 > b) --tr;
  if ((tr + 1) * (tr + 2) / 2 <= b) ++tr;
  const int tc = b - tr * (tr + 1) / 2;
  const bool diag = (tr == tc);

  const int wr = w >> 1, wc = w & 1;
  const int m = l & 15, kg = l >> 4;
  const int rowA0 = tr * 256, colB0 = tc * 256;

  f32x4 acc[4][8] = {};

  // staging: per matrix per stage 2048 slots x 16B (256 rows x 8 chunks).
  // phys slot s -> row s>>3; phys chunk s&7 holds logical chunk (s&7)^(row&7).
  int srow[4], scol[4];
#pragma unroll
  for (int j = 0; j < 4; ++j) {
    int s = j * 512 + tid;
    int r = s >> 3;
    srow[j] = r;
    scol[j] = (s & 7) ^ (r & 7);
  }

  // fragment reads: logical chunks kg and kg+4 (K-permuted; A/B identical)
  const int csw0 = (kg ^ (m & 7)) * 16;
  const int csw1 = ((kg + 4) ^ (m & 7)) * 16;

  // prologue: stage kt=0 into buffer 0
  {
    char* ab = smem;
    char* bb = smem + 32768;
#pragma unroll
    for (int j = 0; j < 4; ++j) {
      const int s = j * 512 + tid;
      gload16((const char*)zn8 + ((size_t)(rowA0 + srow[j]) * D + scol[j] * 16), ab + s * 16);
    }
    if (!diag) {
#pragma unroll
      for (int j = 0; j < 4; ++j) {
        const int s = j * 512 + tid;
        gload16((const char*)zn8 + ((size_t)(colB0 + srow[j]) * D + scol[j] * 16), bb + s * 16);
      }
    }
  }
  __syncthreads();

  for (int kt = 0; kt < 8; ++kt) {
    if (kt < 7) {  // async prefetch kt+1 into other buffer; overlaps MFMA below
      const size_t kb = (size_t)(kt + 1) * 128;
      char* ab = smem + ((kt + 1) & 1) * 65536;
#pragma unroll
      for (int j = 0; j < 4; ++j) {
        const int s = j * 512 + tid;
        gload16((const char*)zn8 + ((size_t)(rowA0 + srow[j]) * D + kb + scol[j] * 16), ab + s * 16);
      }
      if (!diag) {
        char* bb = ab + 32768;
#pragma unroll
        for (int j = 0; j < 4; ++j) {
          const int s = j * 512 + tid;
          gload16((const char*)zn8 + ((size_t)(colB0 + srow[j]) * D + kb + scol[j] * 16), bb + s * 16);
        }
      }
    }
    const char* ab = smem + (kt & 1) * 65536;
    const char* bb = diag ? ab : (ab + 32768);

    lx2 a0[4], a1[4];
#pragma unroll
    for (int mt = 0; mt < 4; ++mt) {
      const char* rp = ab + (wr * 64 + mt * 16 + m) * 128;
      a0[mt] = *(const lx2*)(rp + csw0);
      a1[mt] = *(const lx2*)(rp + csw1);
    }
#pragma unroll
    for (int nt = 0; nt < 8; ++nt) {
      const char* rp = bb + (wc * 128 + nt * 16 + m) * 128;
      const lx2 b0 = *(const lx2*)(rp + csw0);
      const lx2 b1 = *(const lx2*)(rp + csw1);
#pragma unroll
      for (int mt = 0; mt < 4; ++mt) {
        acc[mt][nt] = __builtin_amdgcn_mfma_f32_16x16x32_fp8_fp8(a0[mt].x, b0.x, acc[mt][nt], 0, 0, 0);
        acc[mt][nt] = __builtin_amdgcn_mfma_f32_16x16x32_fp8_fp8(a0[mt].y, b0.y, acc[mt][nt], 0, 0, 0);
        acc[mt][nt] = __builtin_amdgcn_mfma_f32_16x16x32_fp8_fp8(a1[mt].x, b1.x, acc[mt][nt], 0, 0, 0);
        acc[mt][nt] = __builtin_amdgcn_mfma_f32_16x16x32_fp8_fp8(a1[mt].y, b1.y, acc[mt][nt], 0, 0, 0);
      }
    }
    __syncthreads();  // drains prefetch (vmcnt) + guards buffer reuse
  }

  // Epilogue. C/D layout: col=l&15, row=(l>>4)*4+reg.
  const int quad = l >> 4;
  const int col = l & 15;
  float cs[8] = {0.f, 0.f, 0.f, 0.f, 0.f, 0.f, 0.f, 0.f};
#pragma unroll
  for (int mt = 0; mt < 4; ++mt) {
    float rs[4] = {0.f, 0.f, 0.f, 0.f};
#pragma unroll
    for (int nt = 0; nt < 8; ++nt) {
      const int gcol = colB0 + wc * 128 + nt * 16 + col;
#pragma unroll
      for (int r = 0; r < 4; ++r) {
        const int grow = rowA0 + wr * 64 + mt * 16 + quad * 4 + r;
        const float t = acc[mt][nt][r] * ACC_SCALE;
        if (gcol == (grow ^ (N / 2))) {  // pos pair; never in diag tiles
          pos[grow] = t;
          pos[gcol] = t;  // S symmetric
        }
        const float e = (gcol == grow) ? 0.0f : __expf(t - INV_T);
        rs[r] += e;
        cs[nt] += e;
      }
    }
#pragma unroll
    for (int off = 1; off < 16; off <<= 1) {
#pragma unroll
      for (int r = 0; r < 4; ++r) rs[r] += __shfl_xor(rs[r], off, 64);
    }
    if (col == 0) {
#pragma unroll
      for (int r = 0; r < 4; ++r)
        atomicAdd(&rowsum[rowA0 + wr * 64 + mt * 16 + quad * 4 + r], rs[r]);
    }
  }
  if (!diag) {  // col sums = row-sums for block tc rows (symmetry)
#pragma unroll
    for (int nt = 0; nt < 8; ++nt) {
      cs[nt] += __shfl_xor(cs[nt], 16, 64);
      cs[nt] += __shfl_xor(cs[nt], 32, 64);
    }
    if (l < 16) {
#pragma unroll
      for (int nt = 0; nt < 8; ++nt)
        atomicAdd(&rowsum[colB0 + wc * 128 + nt * 16 + l], cs[nt]);
    }
  }
}

// Phase 3: single block: out = mean(-pos + C + log(rowsum)).
__global__ __launch_bounds__(1024) void k_final(const float* __restrict__ rowsum,
                                                const float* __restrict__ pos,
                                                float* __restrict__ out) {
  const int t = threadIdx.x;
  float s = 0.f;
  for (int i = t; i < N; i += 1024) s += INV_T + __logf(rowsum[i]) - pos[i];
#pragma unroll
  for (int off = 32; off > 0; off >>= 1) s += __shfl_down(s, off, 64);
  __shared__ float red[16];
  if ((t & 63) == 0) red[t >> 6] = s;
  __syncthreads();
  if (t == 0) {
    float tot = 0.f;
#pragma unroll
    for (int j = 0; j < 16; ++j) tot += red[j];
    out[0] = tot * (1.0f / N);
  }
}

extern "C" void kernel_launch(void* const* d_in, const int* in_sizes, int n_in,
                              void* d_out, int out_size, void* d_ws, size_t ws_size,
                              hipStream_t stream) {
  const float* z = (const float*)d_in[0];
  float* out = (float*)d_out;
  char* ws = (char*)d_ws;
  unsigned char* zn8 = (unsigned char*)ws;                    // 8 MiB fp8
  float* rowsum = (float*)(ws + (size_t)N * D);               // 32 KiB
  float* pos = (float*)(ws + (size_t)N * D + (size_t)N * 4);  // 32 KiB

  static bool attr_set = false;
  if (!attr_set) {  // host-side attribute, idempotent, not a stream op
    hipFuncSetAttribute((const void*)k_tile,
                        hipFuncAttributeMaxDynamicSharedMemorySize, 131072);
    attr_set = true;
  }

  k_normalize<<<N, 256, 0, stream>>>(z, zn8, rowsum);
  k_tile<<<NTILES, 512, 131072, stream>>>(zn8, rowsum, pos);
  k_final<<<1, 1024, 0, stream>>>(rowsum, pos, out);
}